// Round 1
// baseline (1658.959 us; speedup 1.0000x reference)
//
#include <hip/hip_runtime.h>
#include <math.h>

#define BB      4
#define CC      32
#define HH      120
#define WW      160
#define NHEADS  8
#define HD      20
#define NN      3840          // CC*HH = sequence length in the reshaped view
#define ROWS    3840          // CC*HH projection rows per batch
#define BHPAIRS (BB*NHEADS)   // 32

// ---------------- Projection + head-layout scatter ----------------
// q/k/v head-major: [bh][d][n], n contiguous.
// grid: BB*(ROWS/16)=960 blocks, 256 threads.
__global__ __launch_bounds__(256)
void proj_kernel(const float* __restrict__ x,
                 const float* __restrict__ Wq, const float* __restrict__ bq,
                 const float* __restrict__ Wk, const float* __restrict__ bk,
                 const float* __restrict__ Wv, const float* __restrict__ bv,
                 float* __restrict__ qh, float* __restrict__ kh, float* __restrict__ vh)
{
    __shared__ __align__(16) float xs[16][WW];   // 10 KB
    const int blk = blockIdx.x;
    const int b   = blk / (ROWS/16);
    const int rt  = blk % (ROWS/16);
    const int r0  = rt * 16;
    const float* xb = x + (size_t)b * ROWS * WW;
    for (int idx = threadIdx.x; idx < 16*WW; idx += 256) {
        int rr = idx / WW, ww = idx % WW;
        xs[rr][ww] = xb[(size_t)(r0+rr)*WW + ww];
    }
    __syncthreads();
    const int row = threadIdx.x & 15;
    const int og  = threadIdx.x >> 4;      // 0..15, each handles 10 outputs
    const int r   = r0 + row;
    // raw-reshape head mapping: flat = r*160+o = nh*76800 + d*3840 + n
    const int nh = r / 480;
    const int rm = r % 480;
    const int d  = rm / 24;
    const int n1 = rm % 24;
    const size_t obase = ((size_t)(b*NHEADS + nh)*HD + d)*NN + (size_t)n1*160;
    const float4* xrow = (const float4*)xs[row];
    for (int j = 0; j < 10; ++j) {
        const int o = og*10 + j;
        const float4* wq4 = (const float4*)(Wq + (size_t)o*WW);
        const float4* wk4 = (const float4*)(Wk + (size_t)o*WW);
        const float4* wv4 = (const float4*)(Wv + (size_t)o*WW);
        float aq = bq[o], ak = bk[o], av = bv[o];
        #pragma unroll 8
        for (int w4 = 0; w4 < WW/4; ++w4) {
            float4 xv = xrow[w4];
            float4 a  = wq4[w4];
            aq += xv.x*a.x + xv.y*a.y + xv.z*a.z + xv.w*a.w;
            float4 bb = wk4[w4];
            ak += xv.x*bb.x + xv.y*bb.y + xv.z*bb.z + xv.w*bb.w;
            float4 cc = wv4[w4];
            av += xv.x*cc.x + xv.y*cc.y + xv.z*cc.z + xv.w*cc.w;
        }
        qh[obase + o] = aq;
        kh[obase + o] = ak;
        vh[obase + o] = av;
    }
}

// ---------------- Pass 1: Z[m] = sum_n exp(q[:,m].k[:,n]) ----------------
// Logits bounded (~|e|<=12) -> no max subtraction needed in f32.
// grid: BHPAIRS*(NN/256)=480 blocks, 256 threads; thread owns one m.
__global__ __launch_bounds__(256)
void stats_kernel(const float* __restrict__ qh, const float* __restrict__ kh,
                  float* __restrict__ zinv)
{
    __shared__ __align__(16) float ks[64][HD];   // 5 KB
    const int blk = blockIdx.x;
    const int bh  = blk / (NN/256);
    const int mt  = blk % (NN/256);
    const int m   = mt*256 + threadIdx.x;
    const float* q = qh + (size_t)bh*HD*NN;
    const float* k = kh + (size_t)bh*HD*NN;
    float qr[HD];
    #pragma unroll
    for (int dd = 0; dd < HD; ++dd) qr[dd] = q[(size_t)dd*NN + m];
    float Z = 0.f;
    for (int nb = 0; nb < NN; nb += 64) {
        __syncthreads();
        for (int idx = threadIdx.x; idx < 64*HD; idx += 256) {  // 5 iters
            int dd = idx >> 6, j = idx & 63;
            ks[j][dd] = k[(size_t)dd*NN + nb + j];
        }
        __syncthreads();
        for (int j = 0; j < 64; ++j) {
            float e = 0.f;
            #pragma unroll
            for (int dd = 0; dd < HD; ++dd) e += qr[dd] * ks[j][dd];
            Z += __expf(e);
        }
    }
    zinv[(size_t)bh*NN + m] = 1.f / Z;
}

// ---------------- Pass 2: out[d,n] = sum_m (v[d,m]/Z[m]) * exp(e[m,n]) ----------------
// grid: BHPAIRS*(NN/256)=480 blocks, 256 threads; thread owns one output column n.
__global__ __launch_bounds__(256)
void out_kernel(const float* __restrict__ qh, const float* __restrict__ kh,
                const float* __restrict__ vh, const float* __restrict__ zinv,
                float* __restrict__ y)
{
    __shared__ __align__(16) float qs[64][HD];
    __shared__ __align__(16) float ws[64][HD];   // 10 KB total
    const int blk = blockIdx.x;
    const int bh  = blk / (NN/256);
    const int nt  = blk % (NN/256);
    const int n   = nt*256 + threadIdx.x;
    const int b   = bh / NHEADS, nh = bh % NHEADS;
    const float* q  = qh + (size_t)bh*HD*NN;
    const float* k  = kh + (size_t)bh*HD*NN;
    const float* v  = vh + (size_t)bh*HD*NN;
    const float* zi = zinv + (size_t)bh*NN;
    float kc[HD];
    #pragma unroll
    for (int dd = 0; dd < HD; ++dd) kc[dd] = k[(size_t)dd*NN + n];
    float acc[HD];
    #pragma unroll
    for (int dd = 0; dd < HD; ++dd) acc[dd] = 0.f;
    for (int mb = 0; mb < NN; mb += 64) {
        __syncthreads();
        for (int idx = threadIdx.x; idx < 64*HD; idx += 256) {  // 5 iters
            int dd = idx >> 6, j = idx & 63;
            float zv = zi[mb + j];
            qs[j][dd] = q[(size_t)dd*NN + mb + j];
            ws[j][dd] = v[(size_t)dd*NN + mb + j] * zv;
        }
        __syncthreads();
        for (int j = 0; j < 64; ++j) {
            float e = 0.f;
            #pragma unroll
            for (int dd = 0; dd < HD; ++dd) e += qs[j][dd] * kc[dd];
            float p = __expf(e);
            #pragma unroll
            for (int dd = 0; dd < HD; ++dd) acc[dd] += ws[j][dd] * p;
        }
    }
    // out.transpose(0,2,1,3).reshape: y[b][(d*8+nh)*3840 + n]
    float* yb = y + (size_t)b * CC * HH * WW;
    #pragma unroll
    for (int dd = 0; dd < HD; ++dd) {
        yb[(size_t)(dd*NHEADS + nh)*NN + n] = acc[dd];
    }
}

extern "C" void kernel_launch(void* const* d_in, const int* in_sizes, int n_in,
                              void* d_out, int out_size, void* d_ws, size_t ws_size,
                              hipStream_t stream)
{
    const float* x  = (const float*)d_in[0];
    const float* Wq = (const float*)d_in[1];
    const float* bq = (const float*)d_in[2];
    const float* Wk = (const float*)d_in[3];
    const float* bk = (const float*)d_in[4];
    const float* Wv = (const float*)d_in[5];
    const float* bv = (const float*)d_in[6];
    float* y  = (float*)d_out;
    float* ws = (float*)d_ws;

    const size_t tsz = (size_t)BHPAIRS * HD * NN;   // 2,457,600 floats each
    float* qh   = ws;
    float* kh   = qh + tsz;
    float* vh   = kh + tsz;
    float* zinv = vh + tsz;                          // + 122,880 floats (~30 MB total)

    proj_kernel<<<dim3(BB*(ROWS/16)), dim3(256), 0, stream>>>(
        x, Wq, bq, Wk, bk, Wv, bv, qh, kh, vh);
    stats_kernel<<<dim3(BHPAIRS*(NN/256)), dim3(256), 0, stream>>>(qh, kh, zinv);
    out_kernel<<<dim3(BHPAIRS*(NN/256)), dim3(256), 0, stream>>>(qh, kh, vh, zinv, y);
}

// Round 2
// 458.054 us; speedup vs baseline: 3.6218x; 3.6218x over previous
//
#include <hip/hip_runtime.h>
#include <hip/hip_bf16.h>
#include <math.h>

#define BB   4
#define CC   32
#define HH   120
#define WW   160
#define NH_  8
#define HD   20
#define HDP  32            // head dim padded to 32 (zeros) for K=32 MFMA
#define NN   3840          // sequence length (C*H)
#define ROWS 3840
#define NBH  32            // B * NH

typedef float f32x4 __attribute__((ext_vector_type(4)));
typedef short s16x8 __attribute__((ext_vector_type(8)));
typedef short s16x4 __attribute__((ext_vector_type(4)));

static __device__ __forceinline__ unsigned short f2bf(float x) {
    return __builtin_bit_cast(unsigned short, __float2bfloat16(x));
}
static __device__ __forceinline__ float bf2f(unsigned short u) {
    unsigned v = ((unsigned)u) << 16;
    return __builtin_bit_cast(float, v);
}

#if defined(__has_builtin)
#if __has_builtin(__builtin_amdgcn_mfma_f32_16x16x16bf16_1k)
#define HAVE_MFMA16_1K 1
#endif
#endif

static __device__ __forceinline__ f32x4 mfma16(s16x4 a, s16x4 b, f32x4 c) {
#ifdef HAVE_MFMA16_1K
    return __builtin_amdgcn_mfma_f32_16x16x16bf16_1k(a, b, c, 0, 0, 0);
#else
    asm volatile("v_mfma_f32_16x16x16_bf16 %0, %1, %2, %0" : "+v"(c) : "v"(a), "v"(b));
    return c;
#endif
}
static __device__ __forceinline__ f32x4 mfma32(s16x8 a, s16x8 b, f32x4 c) {
    return __builtin_amdgcn_mfma_f32_16x16x32_bf16(a, b, c, 0, 0, 0);
}

// ---------------- Projection (f32 VALU, known-good) + bf16 layout emit ----
// qt/kt: [bh][n][32] bf16 (d-padded; pad rows pre-zeroed by memset)
// vb:    [bh][20][n]  bf16
__global__ __launch_bounds__(256)
void proj_kernel(const float* __restrict__ x,
                 const float* __restrict__ Wq, const float* __restrict__ bq,
                 const float* __restrict__ Wk, const float* __restrict__ bk,
                 const float* __restrict__ Wv, const float* __restrict__ bv,
                 unsigned short* __restrict__ qt, unsigned short* __restrict__ kt,
                 unsigned short* __restrict__ vb)
{
    __shared__ __align__(16) float xs[16][WW];
    const int blk = blockIdx.x;
    const int b   = blk / (ROWS/16);
    const int rt  = blk % (ROWS/16);
    const int r0  = rt * 16;
    const float* xb = x + (size_t)b * ROWS * WW;
    for (int idx = threadIdx.x; idx < 16*WW; idx += 256) {
        int rr = idx / WW, ww = idx % WW;
        xs[rr][ww] = xb[(size_t)(r0+rr)*WW + ww];
    }
    __syncthreads();
    const int row = threadIdx.x & 15;
    const int og  = threadIdx.x >> 4;
    const int r   = r0 + row;
    const int nh  = r / 480;
    const int rm  = r % 480;
    const int d   = rm / 24;
    const int n1  = rm % 24;
    const int bh  = b*NH_ + nh;
    const float4* xrow = (const float4*)xs[row];
    for (int j = 0; j < 10; ++j) {
        const int o = og*10 + j;
        const float4* wq4 = (const float4*)(Wq + (size_t)o*WW);
        const float4* wk4 = (const float4*)(Wk + (size_t)o*WW);
        const float4* wv4 = (const float4*)(Wv + (size_t)o*WW);
        float aq = bq[o], ak = bk[o], av = bv[o];
        #pragma unroll 8
        for (int w4 = 0; w4 < WW/4; ++w4) {
            float4 xv = xrow[w4];
            float4 a  = wq4[w4];
            aq += xv.x*a.x + xv.y*a.y + xv.z*a.z + xv.w*a.w;
            float4 bb = wk4[w4];
            ak += xv.x*bb.x + xv.y*bb.y + xv.z*bb.z + xv.w*bb.w;
            float4 cc = wv4[w4];
            av += xv.x*cc.x + xv.y*cc.y + xv.z*cc.z + xv.w*cc.w;
        }
        const int n = n1*160 + o;
        qt[((size_t)bh*NN + n)*HDP + d] = f2bf(aq);
        kt[((size_t)bh*NN + n)*HDP + d] = f2bf(ak);
        vb[((size_t)bh*HD + d)*NN + n]  = f2bf(av);
    }
}

// ---------------- Pass 1: zinv[m] = 1 / sum_n exp(E[m,n]) via MFMA -------
// 1 wave per block; wave owns m-tile of 64. A-frags (Q) fixed in regs.
__global__ __launch_bounds__(64)
void zinv_kernel(const unsigned short* __restrict__ qt,
                 const unsigned short* __restrict__ kt,
                 float* __restrict__ zinv)
{
    const int blk  = blockIdx.x;
    const int bh   = blk / (NN/64);
    const int m0   = (blk % (NN/64)) * 64;
    const int lane = threadIdx.x;
    const int g = lane >> 4, c = lane & 15;

    s16x8 qa[4];
    #pragma unroll
    for (int ms = 0; ms < 4; ++ms)
        qa[ms] = *(const s16x8*)(qt + ((size_t)bh*NN + m0 + ms*16 + c)*HDP + g*8);

    const f32x4 zero4 = {0.f, 0.f, 0.f, 0.f};
    f32x4 z[4];
    #pragma unroll
    for (int ms = 0; ms < 4; ++ms) z[ms] = zero4;

    for (int n = 0; n < NN; n += 32) {
        s16x8 kb0 = *(const s16x8*)(kt + ((size_t)bh*NN + n +      c)*HDP + g*8);
        s16x8 kb1 = *(const s16x8*)(kt + ((size_t)bh*NN + n + 16 + c)*HDP + g*8);
        #pragma unroll
        for (int ms = 0; ms < 4; ++ms) {
            f32x4 e0 = mfma32(qa[ms], kb0, zero4);
            f32x4 e1 = mfma32(qa[ms], kb1, zero4);
            #pragma unroll
            for (int rr = 0; rr < 4; ++rr)
                z[ms][rr] += __expf(e0[rr]) + __expf(e1[rr]);
        }
    }
    #pragma unroll
    for (int ms = 0; ms < 4; ++ms) {
        #pragma unroll
        for (int rr = 0; rr < 4; ++rr) {
            float v = z[ms][rr];
            v += __shfl_xor(v, 1);
            v += __shfl_xor(v, 2);
            v += __shfl_xor(v, 4);
            v += __shfl_xor(v, 8);
            if (c == 0)
                zinv[(size_t)bh*NN + m0 + ms*16 + g*4 + rr] = 1.0f / v;
        }
    }
}

// ---------------- vzb[bh][dp][m] = bf16(v[dp][m] * zinv[m]), pad rows 0 --
__global__ __launch_bounds__(256)
void vz_kernel(const unsigned short* __restrict__ vb,
               const float* __restrict__ zinv,
               unsigned short* __restrict__ vzb)
{
    size_t idx = (size_t)blockIdx.x*256 + threadIdx.x;   // over NBH*HDP*NN
    int m  = (int)(idx % NN);
    int t  = (int)(idx / NN);
    int dp = t % HDP;
    int bh = t / HDP;
    float val = 0.f;
    if (dp < HD)
        val = bf2f(vb[((size_t)bh*HD + dp)*NN + m]) * zinv[(size_t)bh*NN + m];
    vzb[idx] = f2bf(val);
}

// ---------------- Pass 2: out = Vz * exp(Q^T K), fully in MFMA -----------
// 1 wave per block; wave owns n-tile of 64 and full d (20->32 padded).
// E D-frag (row=g*4+r, col=c) == PV 16x16x16 B-frag (k=g*4+b, col=c):
// P needs NO cross-lane movement between the two MFMAs.
__global__ __launch_bounds__(64)
void attn_out_kernel(const unsigned short* __restrict__ qt,
                     const unsigned short* __restrict__ kt,
                     const unsigned short* __restrict__ vzb,
                     float* __restrict__ y)
{
    const int blk  = blockIdx.x;
    const int bh   = blk / (NN/64);
    const int n0   = (blk % (NN/64)) * 64;
    const int lane = threadIdx.x;
    const int g = lane >> 4, c = lane & 15;
    const int b = bh >> 3, nh = bh & 7;

    const f32x4 zero4 = {0.f, 0.f, 0.f, 0.f};

    s16x8 kb[4];                       // K B-frags, fixed for whole m loop
    #pragma unroll
    for (int ns = 0; ns < 4; ++ns)
        kb[ns] = *(const s16x8*)(kt + ((size_t)bh*NN + n0 + ns*16 + c)*HDP + g*8);

    f32x4 acc[2][4];
    #pragma unroll
    for (int ds = 0; ds < 2; ++ds)
        #pragma unroll
        for (int ns = 0; ns < 4; ++ns) acc[ds][ns] = zero4;

    for (int m0 = 0; m0 < NN; m0 += 32) {
        s16x8 qa0 = *(const s16x8*)(qt + ((size_t)bh*NN + m0 +      c)*HDP + g*8);
        s16x8 qa1 = *(const s16x8*)(qt + ((size_t)bh*NN + m0 + 16 + c)*HDP + g*8);
        s16x4 va[2][2];                // Vz A-frags: [dsub][msub]
        #pragma unroll
        for (int ds = 0; ds < 2; ++ds)
            #pragma unroll
            for (int ms = 0; ms < 2; ++ms)
                va[ds][ms] = *(const s16x4*)(vzb + ((size_t)bh*HDP + ds*16 + c)*NN
                                                 + m0 + ms*16 + g*4);
        #pragma unroll
        for (int ns = 0; ns < 4; ++ns) {
            f32x4 e0 = mfma32(qa0, kb[ns], zero4);
            f32x4 e1 = mfma32(qa1, kb[ns], zero4);
            s16x4 p0, p1;
            #pragma unroll
            for (int rr = 0; rr < 4; ++rr) {
                p0[rr] = (short)f2bf(__expf(e0[rr]));
                p1[rr] = (short)f2bf(__expf(e1[rr]));
            }
            acc[0][ns] = mfma16(va[0][0], p0, acc[0][ns]);
            acc[0][ns] = mfma16(va[0][1], p1, acc[0][ns]);
            acc[1][ns] = mfma16(va[1][0], p0, acc[1][ns]);
            acc[1][ns] = mfma16(va[1][1], p1, acc[1][ns]);
        }
    }

    float* yb = y + (size_t)b * CC * HH * WW;
    #pragma unroll
    for (int ds = 0; ds < 2; ++ds) {
        #pragma unroll
        for (int ns = 0; ns < 4; ++ns) {
            #pragma unroll
            for (int rr = 0; rr < 4; ++rr) {
                int dd = ds*16 + g*4 + rr;
                if (dd < HD)
                    yb[((size_t)(dd*NH_ + nh))*NN + n0 + ns*16 + c] = acc[ds][ns][rr];
            }
        }
    }
}

extern "C" void kernel_launch(void* const* d_in, const int* in_sizes, int n_in,
                              void* d_out, int out_size, void* d_ws, size_t ws_size,
                              hipStream_t stream)
{
    const float* x  = (const float*)d_in[0];
    const float* Wq = (const float*)d_in[1];
    const float* bq = (const float*)d_in[2];
    const float* Wk = (const float*)d_in[3];
    const float* bk = (const float*)d_in[4];
    const float* Wv = (const float*)d_in[5];
    const float* bv = (const float*)d_in[6];
    float* y = (float*)d_out;

    const size_t QT_E = (size_t)NBH * NN * HDP;      // 3,932,160 bf16
    unsigned short* qt  = (unsigned short*)d_ws;
    unsigned short* kt  = qt + QT_E;
    unsigned short* vb  = kt + QT_E;
    unsigned short* vzb = vb + (size_t)NBH * HD * NN;
    float*          zinv = (float*)(vzb + QT_E);     // total ~29.0 MB

    // zero d-pad columns of qt/kt (proj only writes d<20)
    hipMemsetAsync(qt, 0, 2 * QT_E * sizeof(unsigned short), stream);

    proj_kernel<<<dim3(BB*(ROWS/16)), dim3(256), 0, stream>>>(
        x, Wq, bq, Wk, bk, Wv, bv, qt, kt, vb);
    zinv_kernel<<<dim3(NBH*(NN/64)), dim3(64), 0, stream>>>(qt, kt, zinv);
    vz_kernel<<<dim3((NBH*HDP*NN)/256), dim3(256), 0, stream>>>(vb, zinv, vzb);
    attn_out_kernel<<<dim3(NBH*(NN/64)), dim3(64), 0, stream>>>(qt, kt, vzb, y);
}

// Round 3
// 383.834 us; speedup vs baseline: 4.3221x; 1.1934x over previous
//
#include <hip/hip_runtime.h>
#include <hip/hip_bf16.h>
#include <math.h>

#define BB   4
#define CC   32
#define HH   120
#define WW   160
#define NH_  8
#define HD   20
#define HDP  32            // head dim padded to 32 (zeros) for K=32 MFMA
#define NN   3840          // sequence length (C*H)
#define ROWS 3840
#define NBH  32            // B * NH
#define LOG2E 1.44269504088896f

typedef float f32x4 __attribute__((ext_vector_type(4)));
typedef short s16x8 __attribute__((ext_vector_type(8)));
typedef short s16x4 __attribute__((ext_vector_type(4)));

static __device__ __forceinline__ unsigned short f2bf(float x) {
    return __builtin_bit_cast(unsigned short, __float2bfloat16(x));
}
static __device__ __forceinline__ float bf2f(unsigned short u) {
    unsigned v = ((unsigned)u) << 16;
    return __builtin_bit_cast(float, v);
}
static __device__ __forceinline__ float exp2fast(float x) {
#if defined(__has_builtin) && __has_builtin(__builtin_amdgcn_exp2f)
    return __builtin_amdgcn_exp2f(x);
#else
    float r; asm("v_exp_f32 %0, %1" : "=v"(r) : "v"(x)); return r;
#endif
}

#if defined(__has_builtin)
#if __has_builtin(__builtin_amdgcn_mfma_f32_16x16x16bf16_1k)
#define HAVE_MFMA16_1K 1
#endif
#endif

static __device__ __forceinline__ f32x4 mfma16(s16x4 a, s16x4 b, f32x4 c) {
#ifdef HAVE_MFMA16_1K
    return __builtin_amdgcn_mfma_f32_16x16x16bf16_1k(a, b, c, 0, 0, 0);
#else
    asm volatile("v_mfma_f32_16x16x16_bf16 %0, %1, %2, %0" : "+v"(c) : "v"(a), "v"(b));
    return c;
#endif
}
static __device__ __forceinline__ f32x4 mfma32(s16x8 a, s16x8 b, f32x4 c) {
    return __builtin_amdgcn_mfma_f32_16x16x32_bf16(a, b, c, 0, 0, 0);
}

// ---------------- Projection (f32 VALU) + bf16 layout emit ---------------
// qt: [bh][n][32] bf16, Q PRE-SCALED by log2(e)  (pad cols pre-zeroed)
// kt: [bh][n][32] bf16
// vb: [bh][20][n] bf16
__global__ __launch_bounds__(256)
void proj_kernel(const float* __restrict__ x,
                 const float* __restrict__ Wq, const float* __restrict__ bq,
                 const float* __restrict__ Wk, const float* __restrict__ bk,
                 const float* __restrict__ Wv, const float* __restrict__ bv,
                 unsigned short* __restrict__ qt, unsigned short* __restrict__ kt,
                 unsigned short* __restrict__ vb)
{
    __shared__ __align__(16) float xs[16][WW];
    const int blk = blockIdx.x;
    const int b   = blk / (ROWS/16);
    const int rt  = blk % (ROWS/16);
    const int r0  = rt * 16;
    const float* xb = x + (size_t)b * ROWS * WW;
    for (int idx = threadIdx.x; idx < 16*WW; idx += 256) {
        int rr = idx / WW, ww = idx % WW;
        xs[rr][ww] = xb[(size_t)(r0+rr)*WW + ww];
    }
    __syncthreads();
    const int row = threadIdx.x & 15;
    const int og  = threadIdx.x >> 4;
    const int r   = r0 + row;
    const int nh  = r / 480;
    const int rm  = r % 480;
    const int d   = rm / 24;
    const int n1  = rm % 24;
    const int bh  = b*NH_ + nh;
    const float4* xrow = (const float4*)xs[row];
    for (int j = 0; j < 10; ++j) {
        const int o = og*10 + j;
        const float4* wq4 = (const float4*)(Wq + (size_t)o*WW);
        const float4* wk4 = (const float4*)(Wk + (size_t)o*WW);
        const float4* wv4 = (const float4*)(Wv + (size_t)o*WW);
        float aq = bq[o], ak = bk[o], av = bv[o];
        #pragma unroll 8
        for (int w4 = 0; w4 < WW/4; ++w4) {
            float4 xv = xrow[w4];
            float4 a  = wq4[w4];
            aq += xv.x*a.x + xv.y*a.y + xv.z*a.z + xv.w*a.w;
            float4 bb = wk4[w4];
            ak += xv.x*bb.x + xv.y*bb.y + xv.z*bb.z + xv.w*bb.w;
            float4 cc = wv4[w4];
            av += xv.x*cc.x + xv.y*cc.y + xv.z*cc.z + xv.w*cc.w;
        }
        const int n = n1*160 + o;
        qt[((size_t)bh*NN + n)*HDP + d] = f2bf(aq * LOG2E);
        kt[((size_t)bh*NN + n)*HDP + d] = f2bf(ak);
        vb[((size_t)bh*HD + d)*NN + n]  = f2bf(av);
    }
}

// ---------------- Pass 1: zinv[m] = 1 / sum_n exp2(E[m,n]) ---------------
// 4 waves/block; wave w sums its NN/4 n-range; LDS cross-wave reduce.
__global__ __launch_bounds__(256)
void zinv_kernel(const unsigned short* __restrict__ qt,
                 const unsigned short* __restrict__ kt,
                 float* __restrict__ zinv)
{
    __shared__ float zred[4][64];
    const int blk  = blockIdx.x;
    const int bh   = blk / (NN/64);
    const int m0   = (blk % (NN/64)) * 64;
    const int tid  = threadIdx.x;
    const int wv   = tid >> 6;
    const int lane = tid & 63;
    const int g = lane >> 4, c = lane & 15;

    s16x8 qa[4];
    #pragma unroll
    for (int ms = 0; ms < 4; ++ms)
        qa[ms] = *(const s16x8*)(qt + ((size_t)bh*NN + m0 + ms*16 + c)*HDP + g*8);

    const f32x4 zero4 = {0.f, 0.f, 0.f, 0.f};
    f32x4 z[4];
    #pragma unroll
    for (int ms = 0; ms < 4; ++ms) z[ms] = zero4;

    const int nbeg = wv * (NN/4);
    for (int n = nbeg; n < nbeg + NN/4; n += 32) {
        s16x8 kb0 = *(const s16x8*)(kt + ((size_t)bh*NN + n +      c)*HDP + g*8);
        s16x8 kb1 = *(const s16x8*)(kt + ((size_t)bh*NN + n + 16 + c)*HDP + g*8);
        #pragma unroll
        for (int ms = 0; ms < 4; ++ms) {
            f32x4 e0 = mfma32(qa[ms], kb0, zero4);
            f32x4 e1 = mfma32(qa[ms], kb1, zero4);
            #pragma unroll
            for (int rr = 0; rr < 4; ++rr)
                z[ms][rr] += exp2fast(e0[rr]) + exp2fast(e1[rr]);
        }
    }
    #pragma unroll
    for (int ms = 0; ms < 4; ++ms) {
        #pragma unroll
        for (int rr = 0; rr < 4; ++rr) {
            float v = z[ms][rr];
            v += __shfl_xor(v, 1);
            v += __shfl_xor(v, 2);
            v += __shfl_xor(v, 4);
            v += __shfl_xor(v, 8);
            if (c == 0) zred[wv][ms*16 + g*4 + rr] = v;
        }
    }
    __syncthreads();
    if (tid < 64) {
        float s = zred[0][tid] + zred[1][tid] + zred[2][tid] + zred[3][tid];
        zinv[(size_t)bh*NN + m0 + tid] = 1.0f / s;
    }
}

// ---------------- vzb[bh][dp][m] = bf16(v[dp][m] * zinv[m]), pad rows 0 --
__global__ __launch_bounds__(256)
void vz_kernel(const unsigned short* __restrict__ vb,
               const float* __restrict__ zinv,
               unsigned short* __restrict__ vzb)
{
    size_t idx = (size_t)blockIdx.x*256 + threadIdx.x;   // over NBH*HDP*NN
    int m  = (int)(idx % NN);
    int t  = (int)(idx / NN);
    int dp = t % HDP;
    int bh = t / HDP;
    float val = 0.f;
    if (dp < HD)
        val = bf2f(vb[((size_t)bh*HD + dp)*NN + m]) * zinv[(size_t)bh*NN + m];
    vzb[idx] = f2bf(val);
}

// ---------------- Pass 2: out = Vz * exp2(Q^T K) ------------------------
// 4 waves/block, wave w accumulates its NN/4 m-range; LDS reduce; wave 0 writes.
// E D-frag (row=g*4+r, col=c) == PV 16x16x16 B-frag layout: P stays in-lane.
__global__ __launch_bounds__(256)
void attn_out_kernel(const unsigned short* __restrict__ qt,
                     const unsigned short* __restrict__ kt,
                     const unsigned short* __restrict__ vzb,
                     float* __restrict__ y)
{
    __shared__ float red[3][32][64];   // 24 KB: waves 1..3 partials
    const int blk  = blockIdx.x;
    const int bh   = blk / (NN/64);
    const int n0   = (blk % (NN/64)) * 64;
    const int tid  = threadIdx.x;
    const int wv   = tid >> 6;
    const int lane = tid & 63;
    const int g = lane >> 4, c = lane & 15;
    const int b = bh >> 3, nh = bh & 7;

    const f32x4 zero4 = {0.f, 0.f, 0.f, 0.f};
    const unsigned short* qb = qt  + (size_t)bh*NN*HDP;
    const unsigned short* kbp= kt  + (size_t)bh*NN*HDP;
    const unsigned short* vp = vzb + (size_t)bh*HDP*NN;

    s16x8 kb[4];
    #pragma unroll
    for (int ns = 0; ns < 4; ++ns)
        kb[ns] = *(const s16x8*)(kbp + ((size_t)(n0 + ns*16 + c))*HDP + g*8);

    f32x4 acc[2][4];
    #pragma unroll
    for (int ds = 0; ds < 2; ++ds)
        #pragma unroll
        for (int ns = 0; ns < 4; ++ns) acc[ds][ns] = zero4;

    const int mbeg = wv * (NN/4);
    for (int m0 = mbeg; m0 < mbeg + NN/4; m0 += 32) {
        s16x8 qa0 = *(const s16x8*)(qb + ((size_t)(m0 +      c))*HDP + g*8);
        s16x8 qa1 = *(const s16x8*)(qb + ((size_t)(m0 + 16 + c))*HDP + g*8);
        s16x4 va[2][2];
        #pragma unroll
        for (int ds = 0; ds < 2; ++ds)
            #pragma unroll
            for (int ms = 0; ms < 2; ++ms)
                va[ds][ms] = *(const s16x4*)(vp + ((size_t)(ds*16 + c))*NN
                                                + m0 + ms*16 + g*4);
        #pragma unroll
        for (int ns = 0; ns < 4; ++ns) {
            f32x4 e0 = mfma32(qa0, kb[ns], zero4);
            f32x4 e1 = mfma32(qa1, kb[ns], zero4);
            s16x4 p0, p1;
            #pragma unroll
            for (int rr = 0; rr < 4; ++rr) {
                p0[rr] = (short)f2bf(exp2fast(e0[rr]));
                p1[rr] = (short)f2bf(exp2fast(e1[rr]));
            }
            acc[0][ns] = mfma16(va[0][0], p0, acc[0][ns]);
            acc[0][ns] = mfma16(va[0][1], p1, acc[0][ns]);
            acc[1][ns] = mfma16(va[1][0], p0, acc[1][ns]);
            acc[1][ns] = mfma16(va[1][1], p1, acc[1][ns]);
        }
    }

    float* af = (float*)acc;   // 32 contiguous f32
    if (wv > 0) {
        #pragma unroll
        for (int j = 0; j < 32; ++j) red[wv-1][j][lane] = af[j];
    }
    __syncthreads();
    if (wv == 0) {
        #pragma unroll
        for (int j = 0; j < 32; ++j)
            af[j] += red[0][j][lane] + red[1][j][lane] + red[2][j][lane];
        float* yb = y + (size_t)b * CC * HH * WW;
        #pragma unroll
        for (int ds = 0; ds < 2; ++ds) {
            #pragma unroll
            for (int ns = 0; ns < 4; ++ns) {
                #pragma unroll
                for (int rr = 0; rr < 4; ++rr) {
                    int dd = ds*16 + g*4 + rr;
                    if (dd < HD)
                        yb[((size_t)(dd*NH_ + nh))*NN + n0 + ns*16 + c] = acc[ds][ns][rr];
                }
            }
        }
    }
}

extern "C" void kernel_launch(void* const* d_in, const int* in_sizes, int n_in,
                              void* d_out, int out_size, void* d_ws, size_t ws_size,
                              hipStream_t stream)
{
    const float* x  = (const float*)d_in[0];
    const float* Wq = (const float*)d_in[1];
    const float* bq = (const float*)d_in[2];
    const float* Wk = (const float*)d_in[3];
    const float* bk = (const float*)d_in[4];
    const float* Wv = (const float*)d_in[5];
    const float* bv = (const float*)d_in[6];
    float* y = (float*)d_out;

    const size_t QT_E = (size_t)NBH * NN * HDP;      // 3,932,160 bf16
    unsigned short* qt  = (unsigned short*)d_ws;
    unsigned short* kt  = qt + QT_E;
    unsigned short* vb  = kt + QT_E;
    unsigned short* vzb = vb + (size_t)NBH * HD * NN;
    float*          zinv = (float*)(vzb + QT_E);     // total ~29.0 MB

    // zero d-pad columns of qt/kt (proj only writes d<20)
    hipMemsetAsync(qt, 0, 2 * QT_E * sizeof(unsigned short), stream);

    proj_kernel<<<dim3(BB*(ROWS/16)), dim3(256), 0, stream>>>(
        x, Wq, bq, Wk, bk, Wv, bv, qt, kt, vb);
    zinv_kernel<<<dim3(NBH*(NN/64)), dim3(256), 0, stream>>>(qt, kt, zinv);
    vz_kernel<<<dim3((NBH*HDP*NN)/256), dim3(256), 0, stream>>>(vb, zinv, vzb);
    attn_out_kernel<<<dim3(NBH*(NN/64)), dim3(256), 0, stream>>>(qt, kt, vzb, y);
}

// Round 4
// 262.962 us; speedup vs baseline: 6.3087x; 1.4597x over previous
//
#include <hip/hip_runtime.h>
#include <hip/hip_bf16.h>
#include <math.h>

#define BB   4
#define CC   32
#define HH   120
#define WW   160
#define NH_  8
#define HD   20
#define HDP  32            // head dim padded to 32 (zeros) for K=32 MFMA
#define NN   3840          // sequence length (C*H)
#define ROWS 3840
#define NBH  32            // B * NH
#define LOG2E 1.44269504088896f

typedef float f32x4 __attribute__((ext_vector_type(4)));
typedef short s16x8 __attribute__((ext_vector_type(8)));
typedef short s16x4 __attribute__((ext_vector_type(4)));

static __device__ __forceinline__ unsigned short f2bf(float x) {
    return __builtin_bit_cast(unsigned short, __float2bfloat16(x));
}
static __device__ __forceinline__ float bf2f(unsigned short u) {
    unsigned v = ((unsigned)u) << 16;
    return __builtin_bit_cast(float, v);
}
static __device__ __forceinline__ float exp2fast(float x) {
#if defined(__has_builtin) && __has_builtin(__builtin_amdgcn_exp2f)
    return __builtin_amdgcn_exp2f(x);
#else
    float r; asm("v_exp_f32 %0, %1" : "=v"(r) : "v"(x)); return r;
#endif
}

#if defined(__has_builtin)
#if __has_builtin(__builtin_amdgcn_mfma_f32_16x16x16bf16_1k)
#define HAVE_MFMA16_1K 1
#endif
#endif

static __device__ __forceinline__ f32x4 mfma16(s16x4 a, s16x4 b, f32x4 c) {
#ifdef HAVE_MFMA16_1K
    return __builtin_amdgcn_mfma_f32_16x16x16bf16_1k(a, b, c, 0, 0, 0);
#else
    asm volatile("v_mfma_f32_16x16x16_bf16 %0, %1, %2, %0" : "+v"(c) : "v"(a), "v"(b));
    return c;
#endif
}
static __device__ __forceinline__ f32x4 mfma32(s16x8 a, s16x8 b, f32x4 c) {
    return __builtin_amdgcn_mfma_f32_16x16x32_bf16(a, b, c, 0, 0, 0);
}

// ---------------- W prep: f32 -> bf16 [o][k]; Wq pre-scaled by log2(e) ----
__global__ __launch_bounds__(256)
void wprep_kernel(const float* __restrict__ Wq, const float* __restrict__ Wk,
                  const float* __restrict__ Wv,
                  unsigned short* __restrict__ wqb, unsigned short* __restrict__ wkb,
                  unsigned short* __restrict__ wvb)
{
    int i = blockIdx.x*256 + threadIdx.x;
    if (i < WW*WW) {
        wqb[i] = f2bf(Wq[i] * LOG2E);
        wkb[i] = f2bf(Wk[i]);
        wvb[i] = f2bf(Wv[i]);
    }
}

// ---------------- Projection via MFMA --------------------------------
// grid 240 blocks x 4 waves; wave owns 16 x-rows, computes q,k,v for all
// 160 output cols. A-frags (x rows, bf16) live in regs; B-frags (W) from
// global (L1/L2-cached, shared across all blocks). No LDS.
// qt: [bh][n][32] bf16 (Q pre-scaled by log2e via wqb; pads pre-zeroed)
// kt: [bh][n][32] bf16;  vb: [bh][20][n] bf16
__global__ __launch_bounds__(256)
void proj_mfma_kernel(const float* __restrict__ x,
                      const unsigned short* __restrict__ wqb,
                      const unsigned short* __restrict__ wkb,
                      const unsigned short* __restrict__ wvb,
                      const float* __restrict__ bq, const float* __restrict__ bk,
                      const float* __restrict__ bv,
                      unsigned short* __restrict__ qt, unsigned short* __restrict__ kt,
                      unsigned short* __restrict__ vb)
{
    const int tid  = threadIdx.x;
    const int wv   = tid >> 6;
    const int lane = tid & 63;
    const int g = lane >> 4, c = lane & 15;
    const int r0 = blockIdx.x*64 + wv*16;          // wave's m-subtile base row

    // A-frags: row r0+c, k = s*32 + g*8 .. +7
    s16x8 A[5];
    const float* xrow = x + (size_t)(r0 + c)*WW;
    #pragma unroll
    for (int s = 0; s < 5; ++s) {
        float4 v0 = *(const float4*)(xrow + s*32 + g*8);
        float4 v1 = *(const float4*)(xrow + s*32 + g*8 + 4);
        s16x8 a;
        a[0]=(short)f2bf(v0.x); a[1]=(short)f2bf(v0.y);
        a[2]=(short)f2bf(v0.z); a[3]=(short)f2bf(v0.w);
        a[4]=(short)f2bf(v1.x); a[5]=(short)f2bf(v1.y);
        a[6]=(short)f2bf(v1.z); a[7]=(short)f2bf(v1.w);
        A[s] = a;
    }

    // per-rr output bases (D-frag row = g*4+rr)
    size_t baseqk[4], basev[4];
    #pragma unroll
    for (int rr = 0; rr < 4; ++rr) {
        int R  = r0 + g*4 + rr;
        int b  = R / ROWS;
        int r  = R % ROWS;
        int nh = r / 480;
        int rm = r % 480;
        int d  = rm / 24;
        int n1 = rm % 24;
        int bh = b*NH_ + nh;
        baseqk[rr] = ((size_t)bh*NN + n1*160)*HDP + d;   // + o*HDP
        basev[rr]  = ((size_t)bh*HD + d)*NN + n1*160;    // + o
    }

    const f32x4 zero4 = {0.f, 0.f, 0.f, 0.f};
    for (int nt = 0; nt < 10; ++nt) {
        const size_t wbase = (size_t)(nt*16 + c)*WW;
        f32x4 aq = zero4, ak = zero4, av = zero4;
        #pragma unroll
        for (int s = 0; s < 5; ++s) {
            s16x8 Bq = *(const s16x8*)(wqb + wbase + s*32 + g*8);
            aq = mfma32(A[s], Bq, aq);
            s16x8 Bk = *(const s16x8*)(wkb + wbase + s*32 + g*8);
            ak = mfma32(A[s], Bk, ak);
            s16x8 Bv = *(const s16x8*)(wvb + wbase + s*32 + g*8);
            av = mfma32(A[s], Bv, av);
        }
        const int o = nt*16 + c;
        const float bqv = bq[o]*LOG2E, bkv = bk[o], bvv = bv[o];
        #pragma unroll
        for (int rr = 0; rr < 4; ++rr) {
            qt[baseqk[rr] + (size_t)o*HDP] = f2bf(aq[rr] + bqv);
            kt[baseqk[rr] + (size_t)o*HDP] = f2bf(ak[rr] + bkv);
            vb[basev[rr] + o]              = f2bf(av[rr] + bvv);
        }
    }
}

// ---------------- Pass 1: zinv[m] = 1 / sum_n exp2(E[m,n]) ---------------
// 4 waves/block; wave w sums its NN/4 n-range; LDS cross-wave reduce.
__global__ __launch_bounds__(256)
void zinv_kernel(const unsigned short* __restrict__ qt,
                 const unsigned short* __restrict__ kt,
                 float* __restrict__ zinv)
{
    __shared__ float zred[4][64];
    const int blk  = blockIdx.x;
    const int bh   = blk / (NN/64);
    const int m0   = (blk % (NN/64)) * 64;
    const int tid  = threadIdx.x;
    const int wv   = tid >> 6;
    const int lane = tid & 63;
    const int g = lane >> 4, c = lane & 15;

    s16x8 qa[4];
    #pragma unroll
    for (int ms = 0; ms < 4; ++ms)
        qa[ms] = *(const s16x8*)(qt + ((size_t)bh*NN + m0 + ms*16 + c)*HDP + g*8);

    const f32x4 zero4 = {0.f, 0.f, 0.f, 0.f};
    f32x4 z[4];
    #pragma unroll
    for (int ms = 0; ms < 4; ++ms) z[ms] = zero4;

    const int nbeg = wv * (NN/4);
    for (int n = nbeg; n < nbeg + NN/4; n += 32) {
        s16x8 kb0 = *(const s16x8*)(kt + ((size_t)bh*NN + n +      c)*HDP + g*8);
        s16x8 kb1 = *(const s16x8*)(kt + ((size_t)bh*NN + n + 16 + c)*HDP + g*8);
        #pragma unroll
        for (int ms = 0; ms < 4; ++ms) {
            f32x4 e0 = mfma32(qa[ms], kb0, zero4);
            f32x4 e1 = mfma32(qa[ms], kb1, zero4);
            #pragma unroll
            for (int rr = 0; rr < 4; ++rr)
                z[ms][rr] += exp2fast(e0[rr]) + exp2fast(e1[rr]);
        }
    }
    #pragma unroll
    for (int ms = 0; ms < 4; ++ms) {
        #pragma unroll
        for (int rr = 0; rr < 4; ++rr) {
            float v = z[ms][rr];
            v += __shfl_xor(v, 1);
            v += __shfl_xor(v, 2);
            v += __shfl_xor(v, 4);
            v += __shfl_xor(v, 8);
            if (c == 0) zred[wv][ms*16 + g*4 + rr] = v;
        }
    }
    __syncthreads();
    if (tid < 64) {
        float s = zred[0][tid] + zred[1][tid] + zred[2][tid] + zred[3][tid];
        zinv[(size_t)bh*NN + m0 + tid] = 1.0f / s;
    }
}

// ---------------- vzb[bh][dp][m] = bf16(v[dp][m] * zinv[m]), pad rows 0 --
__global__ __launch_bounds__(256)
void vz_kernel(const unsigned short* __restrict__ vb,
               const float* __restrict__ zinv,
               unsigned short* __restrict__ vzb)
{
    size_t idx = (size_t)blockIdx.x*256 + threadIdx.x;   // over NBH*HDP*NN
    int m  = (int)(idx % NN);
    int t  = (int)(idx / NN);
    int dp = t % HDP;
    int bh = t / HDP;
    float val = 0.f;
    if (dp < HD)
        val = bf2f(vb[((size_t)bh*HD + dp)*NN + m]) * zinv[(size_t)bh*NN + m];
    vzb[idx] = f2bf(val);
}

// ---------------- Pass 2: out = Vz * exp2(Q^T K) ------------------------
// 4 waves/block, wave w accumulates its NN/4 m-range; LDS reduce; wave 0 writes.
// E D-frag (row=g*4+r, col=c) == PV 16x16x16 B-frag layout: P stays in-lane.
__global__ __launch_bounds__(256)
void attn_out_kernel(const unsigned short* __restrict__ qt,
                     const unsigned short* __restrict__ kt,
                     const unsigned short* __restrict__ vzb,
                     float* __restrict__ y)
{
    __shared__ float red[3][32][64];   // 24 KB: waves 1..3 partials
    const int blk  = blockIdx.x;
    const int bh   = blk / (NN/64);
    const int n0   = (blk % (NN/64)) * 64;
    const int tid  = threadIdx.x;
    const int wv   = tid >> 6;
    const int lane = tid & 63;
    const int g = lane >> 4, c = lane & 15;
    const int b = bh >> 3, nh = bh & 7;

    const f32x4 zero4 = {0.f, 0.f, 0.f, 0.f};
    const unsigned short* qb = qt  + (size_t)bh*NN*HDP;
    const unsigned short* kbp= kt  + (size_t)bh*NN*HDP;
    const unsigned short* vp = vzb + (size_t)bh*HDP*NN;

    s16x8 kb[4];
    #pragma unroll
    for (int ns = 0; ns < 4; ++ns)
        kb[ns] = *(const s16x8*)(kbp + ((size_t)(n0 + ns*16 + c))*HDP + g*8);

    f32x4 acc[2][4];
    #pragma unroll
    for (int ds = 0; ds < 2; ++ds)
        #pragma unroll
        for (int ns = 0; ns < 4; ++ns) acc[ds][ns] = zero4;

    const int mbeg = wv * (NN/4);
    for (int m0 = mbeg; m0 < mbeg + NN/4; m0 += 32) {
        s16x8 qa0 = *(const s16x8*)(qb + ((size_t)(m0 +      c))*HDP + g*8);
        s16x8 qa1 = *(const s16x8*)(qb + ((size_t)(m0 + 16 + c))*HDP + g*8);
        s16x4 va[2][2];
        #pragma unroll
        for (int ds = 0; ds < 2; ++ds)
            #pragma unroll
            for (int ms = 0; ms < 2; ++ms)
                va[ds][ms] = *(const s16x4*)(vp + ((size_t)(ds*16 + c))*NN
                                                + m0 + ms*16 + g*4);
        #pragma unroll
        for (int ns = 0; ns < 4; ++ns) {
            f32x4 e0 = mfma32(qa0, kb[ns], zero4);
            f32x4 e1 = mfma32(qa1, kb[ns], zero4);
            s16x4 p0, p1;
            #pragma unroll
            for (int rr = 0; rr < 4; ++rr) {
                p0[rr] = (short)f2bf(exp2fast(e0[rr]));
                p1[rr] = (short)f2bf(exp2fast(e1[rr]));
            }
            acc[0][ns] = mfma16(va[0][0], p0, acc[0][ns]);
            acc[0][ns] = mfma16(va[0][1], p1, acc[0][ns]);
            acc[1][ns] = mfma16(va[1][0], p0, acc[1][ns]);
            acc[1][ns] = mfma16(va[1][1], p1, acc[1][ns]);
        }
    }

    float* af = (float*)acc;   // 32 contiguous f32
    if (wv > 0) {
        #pragma unroll
        for (int j = 0; j < 32; ++j) red[wv-1][j][lane] = af[j];
    }
    __syncthreads();
    if (wv == 0) {
        #pragma unroll
        for (int j = 0; j < 32; ++j)
            af[j] += red[0][j][lane] + red[1][j][lane] + red[2][j][lane];
        float* yb = y + (size_t)b * CC * HH * WW;
        #pragma unroll
        for (int ds = 0; ds < 2; ++ds) {
            #pragma unroll
            for (int ns = 0; ns < 4; ++ns) {
                #pragma unroll
                for (int rr = 0; rr < 4; ++rr) {
                    int dd = ds*16 + g*4 + rr;
                    if (dd < HD)
                        yb[((size_t)(dd*NH_ + nh))*NN + n0 + ns*16 + c] = acc[ds][ns][rr];
                }
            }
        }
    }
}

extern "C" void kernel_launch(void* const* d_in, const int* in_sizes, int n_in,
                              void* d_out, int out_size, void* d_ws, size_t ws_size,
                              hipStream_t stream)
{
    const float* x  = (const float*)d_in[0];
    const float* Wq = (const float*)d_in[1];
    const float* bq = (const float*)d_in[2];
    const float* Wk = (const float*)d_in[3];
    const float* bk = (const float*)d_in[4];
    const float* Wv = (const float*)d_in[5];
    const float* bv = (const float*)d_in[6];
    float* y = (float*)d_out;

    const size_t QT_E = (size_t)NBH * NN * HDP;      // 3,932,160 bf16
    unsigned short* qt  = (unsigned short*)d_ws;
    unsigned short* kt  = qt + QT_E;
    unsigned short* vb  = kt + QT_E;
    unsigned short* vzb = vb + (size_t)NBH * HD * NN;
    float*          zinv = (float*)(vzb + QT_E);
    unsigned short* wqb = (unsigned short*)(zinv + (size_t)NBH*NN);
    unsigned short* wkb = wqb + WW*WW;
    unsigned short* wvb = wkb + WW*WW;               // total ~29.2 MB

    // zero d-pad columns of qt/kt (proj only writes d<20)
    hipMemsetAsync(qt, 0, 2 * QT_E * sizeof(unsigned short), stream);

    wprep_kernel<<<dim3((WW*WW + 255)/256), dim3(256), 0, stream>>>(
        Wq, Wk, Wv, wqb, wkb, wvb);
    proj_mfma_kernel<<<dim3(BB*ROWS/64), dim3(256), 0, stream>>>(
        x, wqb, wkb, wvb, bq, bk, bv, qt, kt, vb);
    zinv_kernel<<<dim3(NBH*(NN/64)), dim3(256), 0, stream>>>(qt, kt, zinv);
    vz_kernel<<<dim3((NBH*HDP*NN)/256), dim3(256), 0, stream>>>(vb, zinv, vzb);
    attn_out_kernel<<<dim3(NBH*(NN/64)), dim3(256), 0, stream>>>(qt, kt, vzb, y);
}